// Round 1
// baseline (11661.933 us; speedup 1.0000x reference)
//
#include <hip/hip_runtime.h>

// Problem constants
#define BB 2
#define CC 256
#define HH 200
#define WW 336
#define NROI 512
#define NCLS 81

// ---------------------------------------------------------------------------
// feat NCHW -> NHWC  (c fastest in dst; C==256 so use shifts/masks)
// ---------------------------------------------------------------------------
__global__ void k_nchw2nhwc(const float* __restrict__ src, float* __restrict__ dst) {
  const int total = BB * CC * HH * WW;
  for (int i = blockIdx.x * blockDim.x + threadIdx.x; i < total;
       i += gridDim.x * blockDim.x) {
    int c = i & 255;
    int r = i >> 8;            // (b*HH + y)*WW + x
    int x = r % WW;
    int t = r / WW;
    int y = t % HH;
    int b = t / HH;
    dst[i] = src[((b * CC + c) * HH + y) * WW + x];
  }
}

// ---------------------------------------------------------------------------
// Weight repacks
// ---------------------------------------------------------------------------
// conv w OIHW [256,256,3,3] -> wT[t=(ky*3+kx)][c][o]
__global__ void k_repack_convw(const float* __restrict__ w, float* __restrict__ wT) {
  int d = blockIdx.x * 256 + threadIdx.x;      // 9*256*256 = 589824
  if (d >= 589824) return;
  int o = d & 255;
  int c = (d >> 8) & 255;
  int t = d >> 16;           // 0..8
  int ky = t / 3, kx = t % 3;
  wT[d] = w[((o * 256 + c) * 3 + ky) * 3 + kx];
}

// deconv mdc IOHW [cin=256, cout=256, 2, 2] -> wd[tap=(r*2+s)][c][o] with SPATIAL FLIP:
// jax conv_transpose(transpose_kernel=False, VALID, stride 2) gives
//   out[2i+r, 2j+s, o] = sum_c x[i,j,c] * mdc[c, o, 1-r, 1-s]
__global__ void k_repack_deconv(const float* __restrict__ mdc, float* __restrict__ wd) {
  int d = blockIdx.x * 256 + threadIdx.x;      // 4*256*256 = 262144
  if (d >= 262144) return;
  int o = d & 255;
  int c = (d >> 8) & 255;
  int tap = d >> 16;          // 0..3
  int r = tap >> 1, s = tap & 1;
  wd[d] = mdc[((c * 256 + o) * 2 + (1 - r)) * 2 + (1 - s)];
}

// mpr [81,256,1,1] -> mprT[c][k]
__global__ void k_repack_mpr(const float* __restrict__ mpr, float* __restrict__ mprT) {
  int d = blockIdx.x * 256 + threadIdx.x;      // 256*81 = 20736
  if (d >= 20736) return;
  int k = d % 81;
  int c = d / 81;
  mprT[d] = mpr[k * 256 + c];
}

// ---------------------------------------------------------------------------
// RoIAlign from NHWC feat. One block per (n, oy, ox), 256 threads = channels.
// FLAT=1: out[n][c*OS*OS + s] (for FC heads);  FLAT=0: NHWC out[(n*OS*OS+s)*256+c]
// ---------------------------------------------------------------------------
template <int OS, int FLAT>
__global__ void k_roialign(const float* __restrict__ featN, const float* __restrict__ boxes,
                           const int* __restrict__ bidx, float* __restrict__ out) {
  const int S = OS * OS;
  int blk = blockIdx.x;
  int n = blk / S;
  int s = blk - n * S;
  int oy = s / OS, ox = s - oy * OS;
  int c = threadIdx.x;
  float x1 = boxes[n * 4 + 0], y1 = boxes[n * 4 + 1];
  float x2 = boxes[n * 4 + 2], y2 = boxes[n * 4 + 3];
  const float* fb = featN + (size_t)bidx[n] * HH * WW * CC;
  const float P = (float)(OS * 2);
  float acc = 0.f;
#pragma unroll
  for (int sy = 0; sy < 2; ++sy)
#pragma unroll
    for (int sx = 0; sx < 2; ++sx) {
      float xs = x1 + ((float)(ox * 2 + sx) + 0.5f) / P * (x2 - x1);
      float ys = y1 + ((float)(oy * 2 + sy) + 0.5f) / P * (y2 - y1);
      xs = fminf(fmaxf(xs, 0.f), (float)(WW - 1));
      ys = fminf(fmaxf(ys, 0.f), (float)(HH - 1));
      int x0 = (int)floorf(xs);
      int y0 = (int)floorf(ys);
      int x1i = min(x0 + 1, WW - 1);
      int y1i = min(y0 + 1, HH - 1);
      float lx = xs - (float)x0, ly = ys - (float)y0;
      float f00 = fb[((y0 * WW + x0) << 8) + c];
      float f01 = fb[((y0 * WW + x1i) << 8) + c];
      float f10 = fb[((y1i * WW + x0) << 8) + c];
      float f11 = fb[((y1i * WW + x1i) << 8) + c];
      acc += f00 * (1.f - ly) * (1.f - lx) + f01 * (1.f - ly) * lx +
             f10 * ly * (1.f - lx) + f11 * ly * lx;
    }
  acc *= 0.25f;
  if (FLAT)
    out[(size_t)n * (CC * S) + c * S + s] = acc;
  else
    out[(((size_t)n * S + s) << 8) + c] = acc;
}

// ---------------------------------------------------------------------------
// Generic fp32 GEMM: C[M,N] = A[M,K] @ B[K,N], optional relu.
// 64x64 tile, BK=16, 256 threads, 4x4 accum per thread.
// mode 0: C row-major (ldc=N).  mode 2: mask scatter — row m encodes (n, i, j)
//   over 14x14, col gn is class; dst = ((n*81+gn)*28 + 2i+ki)*28 + 2j+kj.
// blockIdx.z selects problem {A0,B0,O0} or {A1,B1,O1} (dual-head trick).
// ---------------------------------------------------------------------------
#define GBM 64
#define GBN 64
#define GBK 16

__global__ __launch_bounds__(256) void k_gemm(
    const float* __restrict__ A0, const float* __restrict__ B0, float* __restrict__ O0,
    const float* __restrict__ A1, const float* __restrict__ B1, float* __restrict__ O1,
    int M, int N, int K, int relu, int mode, int ki, int kj) {
  const float* A = (blockIdx.z == 0) ? A0 : A1;
  const float* Bw = (blockIdx.z == 0) ? B0 : B1;
  float* O = (blockIdx.z == 0) ? O0 : O1;

  __shared__ float As[GBK][GBM + 4];
  __shared__ float Bs[GBK][GBN + 4];

  int tid = threadIdx.x;
  int m0 = blockIdx.y * GBM;
  int n0 = blockIdx.x * GBN;
  int tx = tid & 15, ty = tid >> 4;
  int a_k = tid & 15, a_m = tid >> 4;     // A staging: 16 k-cols x 16 rows x 4 passes
  int b_n = tid & 63, b_k = tid >> 6;     // B staging: 64 n-cols x 4 rows x 4 passes

  float acc[4][4] = {};

  for (int k0 = 0; k0 < K; k0 += GBK) {
#pragma unroll
    for (int p = 0; p < 4; ++p) {
      int m = a_m + p * 16;
      int gm = m0 + m;
      float v = 0.f;
      if (gm < M) v = A[(long)gm * K + k0 + a_k];
      As[a_k][m] = v;
    }
#pragma unroll
    for (int p = 0; p < 4; ++p) {
      int kk = b_k + p * 4;
      int gn = n0 + b_n;
      float v = 0.f;
      if (gn < N) v = Bw[(long)(k0 + kk) * N + gn];
      Bs[kk][b_n] = v;
    }
    __syncthreads();
#pragma unroll
    for (int kk = 0; kk < GBK; ++kk) {
      float4 a4 = *reinterpret_cast<const float4*>(&As[kk][ty * 4]);
      float4 b4 = *reinterpret_cast<const float4*>(&Bs[kk][tx * 4]);
      float av[4] = {a4.x, a4.y, a4.z, a4.w};
      float bv[4] = {b4.x, b4.y, b4.z, b4.w};
#pragma unroll
      for (int i = 0; i < 4; ++i)
#pragma unroll
        for (int j = 0; j < 4; ++j) acc[i][j] = fmaf(av[i], bv[j], acc[i][j]);
    }
    __syncthreads();
  }

#pragma unroll
  for (int i = 0; i < 4; ++i) {
    int gm = m0 + ty * 4 + i;
    if (gm >= M) continue;
#pragma unroll
    for (int j = 0; j < 4; ++j) {
      int gn = n0 + tx * 4 + j;
      if (gn >= N) continue;
      float v = acc[i][j];
      if (relu) v = fmaxf(v, 0.f);
      long dst;
      if (mode == 0) {
        dst = (long)gm * N + gn;
      } else {  // mask scatter
        int nimg = gm / 196;
        int s2 = gm - nimg * 196;
        int ii = s2 / 14, jj = s2 - ii * 14;
        dst = (((long)nimg * 81 + gn) * 28 + (2 * ii + ki)) * 28 + (2 * jj + kj);
      }
      O[dst] = v;
    }
  }
}

// ---------------------------------------------------------------------------
// conv3x3 SAME, relu, as implicit GEMM. in NHWC [512*14*14, 256], wT [9][c][o].
// M=100352 (multiple of 64, no guards), N=256, K=9*256 via tap-major loop.
// ---------------------------------------------------------------------------
__global__ __launch_bounds__(256) void k_conv3(const float* __restrict__ in,
                                               const float* __restrict__ wT,
                                               float* __restrict__ out) {
  __shared__ float As[GBK][GBM + 4];
  __shared__ float Bs[GBK][GBN + 4];

  int tid = threadIdx.x;
  int m0 = blockIdx.y * GBM;
  int n0 = blockIdx.x * GBN;
  int tx = tid & 15, ty = tid >> 4;
  int a_k = tid & 15, a_m = tid >> 4;
  int b_n = tid & 63, b_k = tid >> 6;

  // per-thread A row -> (n, y, x)
  int rn[4], ry[4], rx[4];
#pragma unroll
  for (int p = 0; p < 4; ++p) {
    int m = m0 + a_m + p * 16;
    rn[p] = m / 196;
    int s = m - rn[p] * 196;
    ry[p] = s / 14;
    rx[p] = s - ry[p] * 14;
  }

  float acc[4][4] = {};

  for (int t = 0; t < 9; ++t) {
    int ky = t / 3 - 1, kx = t % 3 - 1;
    const float* wt = wT + t * 65536;
    for (int c0 = 0; c0 < 256; c0 += GBK) {
#pragma unroll
      for (int p = 0; p < 4; ++p) {
        int yy = ry[p] + ky, xx = rx[p] + kx;
        float v = 0.f;
        if (yy >= 0 && yy < 14 && xx >= 0 && xx < 14)
          v = in[(((long)rn[p] * 196 + yy * 14 + xx) << 8) + c0 + a_k];
        As[a_k][a_m + p * 16] = v;
      }
#pragma unroll
      for (int p = 0; p < 4; ++p) {
        int kk = b_k + p * 4;
        Bs[kk][b_n] = wt[(c0 + kk) * 256 + n0 + b_n];
      }
      __syncthreads();
#pragma unroll
      for (int kk = 0; kk < GBK; ++kk) {
        float4 a4 = *reinterpret_cast<const float4*>(&As[kk][ty * 4]);
        float4 b4 = *reinterpret_cast<const float4*>(&Bs[kk][tx * 4]);
        float av[4] = {a4.x, a4.y, a4.z, a4.w};
        float bv[4] = {b4.x, b4.y, b4.z, b4.w};
#pragma unroll
        for (int i = 0; i < 4; ++i)
#pragma unroll
          for (int j = 0; j < 4; ++j) acc[i][j] = fmaf(av[i], bv[j], acc[i][j]);
      }
      __syncthreads();
    }
  }

#pragma unroll
  for (int i = 0; i < 4; ++i) {
    int gm = m0 + ty * 4 + i;
#pragma unroll
    for (int j = 0; j < 4; ++j) {
      int gn = n0 + tx * 4 + j;
      out[(long)gm * 256 + gn] = fmaxf(acc[i][j], 0.f);
    }
  }
}

// ---------------------------------------------------------------------------
// kernel_launch
// ---------------------------------------------------------------------------
extern "C" void kernel_launch(void* const* d_in, const int* in_sizes, int n_in,
                              void* d_out, int out_size, void* d_ws, size_t ws_size,
                              hipStream_t stream) {
  (void)in_sizes; (void)n_in; (void)out_size; (void)ws_size;
  const float* feat = (const float*)d_in[0];
  const float* boxes = (const float*)d_in[1];
  const float* bw1 = (const float*)d_in[2];
  const float* bw2 = (const float*)d_in[3];
  const float* bwo = (const float*)d_in[4];
  const float* cw1 = (const float*)d_in[5];
  const float* cw2 = (const float*)d_in[6];
  const float* cwo = (const float*)d_in[7];
  const float* m1 = (const float*)d_in[8];
  const float* m2 = (const float*)d_in[9];
  const float* m3 = (const float*)d_in[10];
  const float* m4 = (const float*)d_in[11];
  const float* mdc = (const float*)d_in[12];
  const float* mpr = (const float*)d_in[13];
  const int* bidx = (const int*)d_in[14];

  float* ws = (float*)d_ws;
  float* featN = ws;                         // 34,406,400 floats (bufA aliases this)
  float* bufA = featN;
  float* r7 = ws + 34406400;                 // 512*12544 = 6,422,528
  float* h1b = r7 + 6422528;                 // 512*1024 each
  float* h1c = h1b + 524288;
  float* h2b = h1c + 524288;
  float* h2c = h2b + 524288;
  float* r14 = h2c + 524288;                 // 100352*256 = 25,690,112
  float* bufB = r14 + 25690112;              // 25,690,112
  float* wT = bufB + 25690112;               // 4 * 589,824
  float* wd = wT + 4 * 589824;               // 262,144
  float* mprT = wd + 262144;                 // 20,736
  // total: 96,948,480 floats = 388 MB of ws

  float* outBox = (float*)d_out;             // [512,324]
  float* outCls = outBox + 512 * 324;        // [512,81]
  float* outMask = outCls + 512 * 81;        // [512,81,28,28]

  // Stage 0: layout transforms
  k_nchw2nhwc<<<dim3(8192), dim3(256), 0, stream>>>(feat, featN);
  const float* mw[4] = {m1, m2, m3, m4};
  for (int t = 0; t < 4; ++t)
    k_repack_convw<<<dim3(2304), dim3(256), 0, stream>>>(mw[t], wT + t * 589824);
  k_repack_deconv<<<dim3(1024), dim3(256), 0, stream>>>(mdc, wd);
  k_repack_mpr<<<dim3(81), dim3(256), 0, stream>>>(mpr, mprT);

  // Stage 1: RoIAlign
  k_roialign<7, 1><<<dim3(512 * 49), dim3(256), 0, stream>>>(featN, boxes, bidx, r7);
  k_roialign<14, 0><<<dim3(512 * 196), dim3(256), 0, stream>>>(featN, boxes, bidx, r14);

  // Stage 2: FC heads (dual box/cls via grid.z)
  k_gemm<<<dim3(16, 8, 2), 256, 0, stream>>>(r7, bw1, h1b, r7, cw1, h1c,
                                             512, 1024, 12544, 1, 0, 0, 0);
  k_gemm<<<dim3(16, 8, 2), 256, 0, stream>>>(h1b, bw2, h2b, h1c, cw2, h2c,
                                             512, 1024, 1024, 1, 0, 0, 0);
  k_gemm<<<dim3(6, 8, 1), 256, 0, stream>>>(h2b, bwo, outBox, h2b, bwo, outBox,
                                            512, 324, 1024, 0, 0, 0, 0);
  k_gemm<<<dim3(2, 8, 1), 256, 0, stream>>>(h2c, cwo, outCls, h2c, cwo, outCls,
                                            512, 81, 1024, 0, 0, 0, 0);

  // Stage 3: mask conv tower (NHWC ping-pong; bufA reuses feat region — safe,
  // all feat readers are done by stream order)
  k_conv3<<<dim3(4, 1568), 256, 0, stream>>>(r14, wT + 0 * 589824, bufA);
  k_conv3<<<dim3(4, 1568), 256, 0, stream>>>(bufA, wT + 1 * 589824, bufB);
  k_conv3<<<dim3(4, 1568), 256, 0, stream>>>(bufB, wT + 2 * 589824, r14);
  k_conv3<<<dim3(4, 1568), 256, 0, stream>>>(r14, wT + 3 * 589824, bufA);

  // Stage 4: deconv (4 parity taps, kernel pre-flipped in wd) + relu, then 1x1
  // conv to 81 classes scattered into NCHW mask output. Taps partition the
  // 28x28 grid by parity -> no accumulation across taps.
  for (int r = 0; r < 2; ++r)
    for (int s = 0; s < 2; ++s) {
      int tap = r * 2 + s;
      k_gemm<<<dim3(4, 1568, 1), 256, 0, stream>>>(
          bufA, wd + tap * 65536, bufB, bufA, wd, bufB,
          100352, 256, 256, 1, 0, 0, 0);
      k_gemm<<<dim3(2, 1568, 1), 256, 0, stream>>>(
          bufB, mprT, outMask, bufB, mprT, outMask,
          100352, 81, 256, 0, 2, r, s);
    }
}

// Round 2
// 2101.854 us; speedup vs baseline: 5.5484x; 5.5484x over previous
//
#include <hip/hip_runtime.h>
#include <stdint.h>

#define BB 2
#define CC 256
#define HH 200
#define WW 336
#define NROI 512
#define NCLS 81

typedef __attribute__((ext_vector_type(8))) short bf16x8;
typedef __attribute__((ext_vector_type(4))) float f32x4;

__device__ inline unsigned short f2bf(float f) {
  unsigned int u = __builtin_bit_cast(unsigned int, f);
  u += 0x7fffu + ((u >> 16) & 1u);
  return (unsigned short)(u >> 16);
}

// async global->LDS, 16 B per lane; LDS dest = uniform base + lane*16
__device__ inline void gl_lds(const void* gp, void* lp) {
  __builtin_amdgcn_global_load_lds(
      (const __attribute__((address_space(1))) unsigned int*)gp,
      (__attribute__((address_space(3))) unsigned int*)lp, 16, 0, 0);
}

// ---------------------------------------------------------------------------
// feat NCHW -> NHWC fp32, tiled transpose (coalesced both sides)
// per batch: [256][67200] -> [67200][256]; grid (2100, 8, 2), block 256
// ---------------------------------------------------------------------------
__global__ void k_nchw2nhwc(const float* __restrict__ src, float* __restrict__ dst) {
  __shared__ float t[32][33];
  int b = blockIdx.z;
  int p0 = blockIdx.x * 32;
  int c0 = blockIdx.y * 32;
  int tx = threadIdx.x & 31, ty = threadIdx.x >> 5;
  const float* s = src + (size_t)b * CC * HH * WW;
  float* d = dst + (size_t)b * CC * HH * WW;
#pragma unroll
  for (int q = 0; q < 4; ++q)
    t[ty + q * 8][tx] = s[(size_t)(c0 + ty + q * 8) * (HH * WW) + p0 + tx];
  __syncthreads();
#pragma unroll
  for (int q = 0; q < 4; ++q)
    d[(size_t)(p0 + ty + q * 8) * CC + c0 + tx] = t[tx][ty + q * 8];
}

// ---------------------------------------------------------------------------
// Weight repacks (fp32 -> bf16, Bt layout [out][in] so GEMM reads k-contig)
// ---------------------------------------------------------------------------
// conv OIHW [256,256,3,3] -> wTb[t][o][c]
__global__ void k_repack_convw(const float* __restrict__ w, unsigned short* __restrict__ wT) {
  int d = blockIdx.x * 256 + threadIdx.x;  // 9*256*256
  if (d >= 589824) return;
  int c = d & 255, o = (d >> 8) & 255, t = d >> 16;
  wT[d] = f2bf(w[o * 2304 + c * 9 + t]);
}

// deconv IOHW [256,256,2,2] -> wdb[tap][o][c], spatially flipped:
// out[2i+r,2j+s,o] += x[i,j,c]*mdc[c,o,1-r,1-s]
__global__ void k_repack_deconv(const float* __restrict__ mdc, unsigned short* __restrict__ wd) {
  int d = blockIdx.x * 256 + threadIdx.x;  // 4*256*256
  if (d >= 262144) return;
  int c = d & 255, o = (d >> 8) & 255, tap = d >> 16;
  int r = tap >> 1, s = tap & 1;
  wd[d] = f2bf(mdc[c * 1024 + o * 4 + (1 - r) * 2 + (1 - s)]);
}

// mpr [81,256] -> mprTb[o][c], o padded to 128 with zeros
__global__ void k_repack_mpr(const float* __restrict__ mpr, unsigned short* __restrict__ mT) {
  int d = blockIdx.x * 256 + threadIdx.x;  // 128*256
  if (d >= 32768) return;
  int c = d & 255, o = d >> 8;
  mT[d] = (o < 81) ? f2bf(mpr[o * 256 + c]) : (unsigned short)0;
}

// w1 [12544][1024] -> dst[n][k'] with k' = s*256 + c  (orig k = c*49+s)
// grid (49, 8, 32), block 256
__global__ void k_repack_w1(const float* __restrict__ src, unsigned short* __restrict__ dst) {
  __shared__ float t[32][33];
  int s = blockIdx.x;
  int c0 = blockIdx.y * 32;
  int n0 = blockIdx.z * 32;
  int tx = threadIdx.x & 31, ty = threadIdx.x >> 5;
#pragma unroll
  for (int q = 0; q < 4; ++q)
    t[ty + q * 8][tx] = src[(size_t)((c0 + ty + q * 8) * 49 + s) * 1024 + n0 + tx];
  __syncthreads();
#pragma unroll
  for (int q = 0; q < 4; ++q)
    dst[(size_t)(n0 + ty + q * 8) * 12544 + s * 256 + c0 + tx] = f2bf(t[tx][ty + q * 8]);
}

// generic: src [K][Nreal] f32 -> dst [Nphys][K] bf16 (rows >= Nreal zero)
// grid (K/32, Nphys/32), block 256
__global__ void k_transpose_w(const float* __restrict__ src, unsigned short* __restrict__ dst,
                              int K, int Nreal, int Nphys) {
  __shared__ float t[32][33];
  int k0 = blockIdx.x * 32;
  int n0 = blockIdx.y * 32;
  int tx = threadIdx.x & 31, ty = threadIdx.x >> 5;
#pragma unroll
  for (int q = 0; q < 4; ++q) {
    int n = n0 + tx;
    t[ty + q * 8][tx] = (n < Nreal) ? src[(size_t)(k0 + ty + q * 8) * Nreal + n] : 0.f;
  }
  __syncthreads();
#pragma unroll
  for (int q = 0; q < 4; ++q) {
    int n = n0 + ty + q * 8;
    if (n < Nphys) dst[(size_t)n * K + k0 + tx] = f2bf(t[tx][ty + q * 8]);
  }
}

// ---------------------------------------------------------------------------
// RoIAlign from fp32 NHWC feat, bf16 out. Block per (n, s), 256 thr = channels.
// OS=7 : out r7b[n*12544 + s*256 + c]           (FC-head A, k' = s*256+c)
// OS=14: out r14p[(n*256 + (y+1)*16 + (x+1))*256 + c]  (padded conv input)
// ---------------------------------------------------------------------------
template <int OS>
__global__ void k_roialign(const float* __restrict__ featN, const float* __restrict__ boxes,
                           const int* __restrict__ bidx, unsigned short* __restrict__ out) {
  const int S = OS * OS;
  int blk = blockIdx.x;
  int n = blk / S;
  int s = blk - n * S;
  int oy = s / OS, ox = s - oy * OS;
  int c = threadIdx.x;
  float x1 = boxes[n * 4 + 0], y1 = boxes[n * 4 + 1];
  float x2 = boxes[n * 4 + 2], y2 = boxes[n * 4 + 3];
  const float* fb = featN + (size_t)bidx[n] * HH * WW * CC;
  const float P = (float)(OS * 2);
  float acc = 0.f;
#pragma unroll
  for (int sy = 0; sy < 2; ++sy)
#pragma unroll
    for (int sx = 0; sx < 2; ++sx) {
      float xs = x1 + ((float)(ox * 2 + sx) + 0.5f) / P * (x2 - x1);
      float ys = y1 + ((float)(oy * 2 + sy) + 0.5f) / P * (y2 - y1);
      xs = fminf(fmaxf(xs, 0.f), (float)(WW - 1));
      ys = fminf(fmaxf(ys, 0.f), (float)(HH - 1));
      int x0 = (int)floorf(xs);
      int y0 = (int)floorf(ys);
      int x1i = min(x0 + 1, WW - 1);
      int y1i = min(y0 + 1, HH - 1);
      float lx = xs - (float)x0, ly = ys - (float)y0;
      float f00 = fb[((y0 * WW + x0) << 8) + c];
      float f01 = fb[((y0 * WW + x1i) << 8) + c];
      float f10 = fb[((y1i * WW + x0) << 8) + c];
      float f11 = fb[((y1i * WW + x1i) << 8) + c];
      acc += f00 * (1.f - ly) * (1.f - lx) + f01 * (1.f - ly) * lx +
             f10 * ly * (1.f - lx) + f11 * ly * lx;
    }
  acc *= 0.25f;
  if (OS == 7) {
    out[(size_t)n * 12544 + s * 256 + c] = f2bf(acc);
  } else {
    int slot = n * 256 + (oy + 1) * 16 + (ox + 1);
    out[((size_t)slot << 8) + c] = f2bf(acc);
  }
}

// ---------------------------------------------------------------------------
// bf16 MFMA GEMM, m97 structure: 128x128 tile, BK=32, 4 waves 2x2,
// global_load_lds width 16, A [M][K] bf16, Bt [Nphys][K] bf16.
// mode 0: bf16 out [gm*ldO+gn] (opt relu)
// mode 1: fp32 out [gm*ldO+gn], guarded gn < Nreal
// mode 2: fp32 mask-scatter, guarded gn < Nreal
// grid.z picks problem {A0,Bt0,O0} / {A1,Bt1,O1}
// ---------------------------------------------------------------------------
#define TM 128
#define TN 128
#define TK 32

__global__ __launch_bounds__(256) void k_gemm_bf16(
    const unsigned short* __restrict__ A0, const unsigned short* __restrict__ Bt0, void* __restrict__ O0p,
    const unsigned short* __restrict__ A1, const unsigned short* __restrict__ Bt1, void* __restrict__ O1p,
    int K, int Nreal, int ldO, int mode, int relu, int ki, int kj) {
  const unsigned short* A = blockIdx.z ? A1 : A0;
  const unsigned short* Bt = blockIdx.z ? Bt1 : Bt0;
  void* Op = blockIdx.z ? O1p : O0p;

  __shared__ unsigned short As[TM * TK];
  __shared__ unsigned short Bs[TN * TK];

  int tid = threadIdx.x, lane = tid & 63, w = tid >> 6;
  int m0 = blockIdx.y * TM, n0 = blockIdx.x * TN;
  int lr = lane >> 2, lc = (lane & 3) * 8;

  const unsigned short* aP[2];
  const unsigned short* bP[2];
  unsigned short* asL[2];
  unsigned short* bsL[2];
#pragma unroll
  for (int s = 0; s < 2; ++s) {
    int seg = w * 2 + s;
    aP[s] = A + (size_t)(m0 + seg * 16 + lr) * K + lc;
    bP[s] = Bt + (size_t)(n0 + seg * 16 + lr) * K + lc;
    asL[s] = As + seg * 512;
    bsL[s] = Bs + seg * 512;
  }

  f32x4 acc[4][4] = {};
  int wm = (w & 1) * 64, wn = (w >> 1) * 64;
  int qa = (lane >> 4) * 8, rl = lane & 15;

  for (int k0 = 0; k0 < K; k0 += TK) {
    gl_lds(aP[0], asL[0]);
    gl_lds(aP[1], asL[1]);
    gl_lds(bP[0], bsL[0]);
    gl_lds(bP[1], bsL[1]);
    aP[0] += TK; aP[1] += TK; bP[0] += TK; bP[1] += TK;
    __syncthreads();
    bf16x8 af[4], bfr[4];
#pragma unroll
    for (int i = 0; i < 4; ++i)
      af[i] = *(const bf16x8*)&As[(wm + i * 16 + rl) * TK + qa];
#pragma unroll
    for (int j = 0; j < 4; ++j)
      bfr[j] = *(const bf16x8*)&Bs[(wn + j * 16 + rl) * TK + qa];
#pragma unroll
    for (int i = 0; i < 4; ++i)
#pragma unroll
      for (int j = 0; j < 4; ++j)
        acc[i][j] = __builtin_amdgcn_mfma_f32_16x16x32_bf16(af[i], bfr[j], acc[i][j], 0, 0, 0);
    __syncthreads();
  }

  int col = lane & 15, rquad = (lane >> 4) * 4;
#pragma unroll
  for (int i = 0; i < 4; ++i) {
#pragma unroll
    for (int j = 0; j < 4; ++j) {
      int gn = n0 + wn + j * 16 + col;
#pragma unroll
      for (int r = 0; r < 4; ++r) {
        int gm = m0 + wm + i * 16 + rquad + r;
        float v = acc[i][j][r];
        if (relu) v = fmaxf(v, 0.f);
        if (mode == 0) {
          ((unsigned short*)Op)[(size_t)gm * ldO + gn] = f2bf(v);
        } else if (mode == 1) {
          if (gn < Nreal) ((float*)Op)[(size_t)gm * ldO + gn] = v;
        } else {
          if (gn < Nreal) {
            int nimg = gm / 196;
            int s2 = gm - nimg * 196;
            int ii = s2 / 14, jj = s2 - ii * 14;
            size_t dst = (((size_t)nimg * 81 + gn) * 28 + (2 * ii + ki)) * 28 + (2 * jj + kj);
            ((float*)Op)[dst] = v;
          }
        }
      }
    }
  }
}

// ---------------------------------------------------------------------------
// conv3x3 SAME + relu as implicit bf16 MFMA GEMM over padded NHWC input.
// act: [512*256 slots][256] bf16 (16x16 padded spatial); wt: [9][o][c] bf16.
// M = 100352 (grid.y=784), N = 256 (grid.x=2), K = 9*256 tap-major.
// PADOUT=1: write padded interior; PADOUT=0: flat [100352][256].
// ---------------------------------------------------------------------------
template <int PADOUT>
__global__ __launch_bounds__(256) void k_conv3m(const unsigned short* __restrict__ act,
                                                const unsigned short* __restrict__ wt,
                                                unsigned short* __restrict__ out) {
  __shared__ unsigned short As[TM * TK];
  __shared__ unsigned short Bs[TN * TK];

  int tid = threadIdx.x, lane = tid & 63, w = tid >> 6;
  int m0 = blockIdx.y * TM, n0 = blockIdx.x * TN;
  int lr = lane >> 2, lc = (lane & 3) * 8;

  const unsigned short* aB[2];
  const unsigned short* bB[2];
  unsigned short* asL[2];
  unsigned short* bsL[2];
#pragma unroll
  for (int s = 0; s < 2; ++s) {
    int seg = w * 2 + s;
    int m = m0 + seg * 16 + lr;
    int n = m / 196;
    int rem = m - n * 196;
    int y = rem / 14, x = rem - y * 14;
    int slot = n * 256 + (y + 1) * 16 + (x + 1);
    aB[s] = act + ((size_t)slot << 8) + lc;
    bB[s] = wt + (size_t)(n0 + seg * 16 + lr) * 256 + lc;
    asL[s] = As + seg * 512;
    bsL[s] = Bs + seg * 512;
  }

  f32x4 acc[4][4] = {};
  int wm = (w & 1) * 64, wn = (w >> 1) * 64;
  int qa = (lane >> 4) * 8, rl = lane & 15;

  for (int ky = -1; ky <= 1; ++ky) {
    for (int kx = -1; kx <= 1; ++kx) {
      int aoff = (ky * 16 + kx) * 256;
      int boff = ((ky + 1) * 3 + (kx + 1)) * 65536;
      for (int c0 = 0; c0 < 256; c0 += TK) {
        gl_lds(aB[0] + aoff + c0, asL[0]);
        gl_lds(aB[1] + aoff + c0, asL[1]);
        gl_lds(bB[0] + boff + c0, bsL[0]);
        gl_lds(bB[1] + boff + c0, bsL[1]);
        __syncthreads();
        bf16x8 af[4], bfr[4];
#pragma unroll
        for (int i = 0; i < 4; ++i)
          af[i] = *(const bf16x8*)&As[(wm + i * 16 + rl) * TK + qa];
#pragma unroll
        for (int j = 0; j < 4; ++j)
          bfr[j] = *(const bf16x8*)&Bs[(wn + j * 16 + rl) * TK + qa];
#pragma unroll
        for (int i = 0; i < 4; ++i)
#pragma unroll
          for (int j = 0; j < 4; ++j)
            acc[i][j] = __builtin_amdgcn_mfma_f32_16x16x32_bf16(af[i], bfr[j], acc[i][j], 0, 0, 0);
        __syncthreads();
      }
    }
  }

  int col = lane & 15, rquad = (lane >> 4) * 4;
#pragma unroll
  for (int i = 0; i < 4; ++i) {
#pragma unroll
    for (int r = 0; r < 4; ++r) {
      int gm = m0 + wm + i * 16 + rquad + r;
      size_t rowbase;
      if (PADOUT) {
        int n = gm / 196;
        int rem = gm - n * 196;
        int y = rem / 14, x = rem - y * 14;
        rowbase = ((size_t)(n * 256 + (y + 1) * 16 + (x + 1))) << 8;
      } else {
        rowbase = (size_t)gm << 8;
      }
#pragma unroll
      for (int j = 0; j < 4; ++j) {
        int gn = n0 + wn + j * 16 + col;
        out[rowbase + gn] = f2bf(fmaxf(acc[i][j][r], 0.f));
      }
    }
  }
}

// ---------------------------------------------------------------------------
// kernel_launch
// ---------------------------------------------------------------------------
extern "C" void kernel_launch(void* const* d_in, const int* in_sizes, int n_in,
                              void* d_out, int out_size, void* d_ws, size_t ws_size,
                              hipStream_t stream) {
  (void)in_sizes; (void)n_in; (void)out_size; (void)ws_size;
  const float* feat = (const float*)d_in[0];
  const float* boxes = (const float*)d_in[1];
  const float* bw1 = (const float*)d_in[2];
  const float* bw2 = (const float*)d_in[3];
  const float* bwo = (const float*)d_in[4];
  const float* cw1 = (const float*)d_in[5];
  const float* cw2 = (const float*)d_in[6];
  const float* cwo = (const float*)d_in[7];
  const float* m1 = (const float*)d_in[8];
  const float* m2 = (const float*)d_in[9];
  const float* m3 = (const float*)d_in[10];
  const float* m4 = (const float*)d_in[11];
  const float* mdc = (const float*)d_in[12];
  const float* mpr = (const float*)d_in[13];
  const int* bidx = (const int*)d_in[14];

  // ---- workspace layout (bytes; total 386,465,792 <= proven 387,793,920) ----
  char* p = (char*)d_ws;
  float* featN = (float*)p;                  p += 137625600;  // fp32 NHWC feat
  unsigned short* cbufA = (unsigned short*)featN;             // alias (67,108,864 B)
  unsigned short* cbufB = (unsigned short*)((char*)featN + 67108864);
  unsigned short* r14p = (unsigned short*)p; p += 67108864;   // padded conv input
  unsigned short* dflat = (unsigned short*)p; p += 51380224;  // conv4 out, flat
  unsigned short* ddec = (unsigned short*)p;  p += 51380224;  // deconv tap out
  unsigned short* r7b = (unsigned short*)p;   p += 12845056;  // [512][12544]
  unsigned short* h1b = (unsigned short*)p;   p += 1048576;
  unsigned short* h1c = (unsigned short*)p;   p += 1048576;
  unsigned short* h2b = (unsigned short*)p;   p += 1048576;
  unsigned short* h2c = (unsigned short*)p;   p += 1048576;
  unsigned short* wTb = (unsigned short*)p;   p += 4718592;   // 4 convs [9][o][c]
  unsigned short* wdb = (unsigned short*)p;   p += 524288;    // [4][o][c]
  unsigned short* mprTb = (unsigned short*)p; p += 65536;     // [128][256]
  unsigned short* bw1b = (unsigned short*)p;  p += 25690112;  // [1024][12544]
  unsigned short* cw1b = (unsigned short*)p;  p += 25690112;
  unsigned short* bw2b = (unsigned short*)p;  p += 2097152;   // [1024][1024]
  unsigned short* cw2b = (unsigned short*)p;  p += 2097152;
  unsigned short* bwob = (unsigned short*)p;  p += 786432;    // [384][1024]
  unsigned short* cwob = (unsigned short*)p;  p += 262144;    // [128][1024]

  float* outBox = (float*)d_out;              // [512][324]
  float* outCls = outBox + 512 * 324;         // [512][81]
  float* outMask = outCls + 512 * 81;         // [512][81][28][28]

  // ---- stage 0: layout transforms ----
  k_nchw2nhwc<<<dim3(2100, 8, 2), 256, 0, stream>>>(feat, featN);
  const float* mw[4] = {m1, m2, m3, m4};
  for (int t = 0; t < 4; ++t)
    k_repack_convw<<<dim3(2304), 256, 0, stream>>>(mw[t], wTb + t * 589824);
  k_repack_deconv<<<dim3(1024), 256, 0, stream>>>(mdc, wdb);
  k_repack_mpr<<<dim3(128), 256, 0, stream>>>(mpr, mprTb);
  k_repack_w1<<<dim3(49, 8, 32), 256, 0, stream>>>(bw1, bw1b);
  k_repack_w1<<<dim3(49, 8, 32), 256, 0, stream>>>(cw1, cw1b);
  k_transpose_w<<<dim3(32, 32), 256, 0, stream>>>(bw2, bw2b, 1024, 1024, 1024);
  k_transpose_w<<<dim3(32, 32), 256, 0, stream>>>(cw2, cw2b, 1024, 1024, 1024);
  k_transpose_w<<<dim3(32, 12), 256, 0, stream>>>(bwo, bwob, 1024, 324, 384);
  k_transpose_w<<<dim3(32, 4), 256, 0, stream>>>(cwo, cwob, 1024, 81, 128);

  // ---- stage 1: RoIAlign (r14p borders must be zero before interior fill) ----
  hipMemsetAsync(r14p, 0, 67108864, stream);
  k_roialign<7><<<dim3(512 * 49), 256, 0, stream>>>(featN, boxes, bidx, r7b);
  k_roialign<14><<<dim3(512 * 196), 256, 0, stream>>>(featN, boxes, bidx, r14p);

  // ---- stage 2: FC heads (dual box/cls via grid.z) ----
  k_gemm_bf16<<<dim3(8, 4, 2), 256, 0, stream>>>(r7b, bw1b, h1b, r7b, cw1b, h1c,
                                                 12544, 1024, 1024, 0, 1, 0, 0);
  k_gemm_bf16<<<dim3(8, 4, 2), 256, 0, stream>>>(h1b, bw2b, h2b, h1c, cw2b, h2c,
                                                 1024, 1024, 1024, 0, 1, 0, 0);
  k_gemm_bf16<<<dim3(3, 4, 1), 256, 0, stream>>>(h2b, bwob, outBox, h2b, bwob, outBox,
                                                 1024, 324, 324, 1, 0, 0, 0);
  k_gemm_bf16<<<dim3(1, 4, 1), 256, 0, stream>>>(h2c, cwob, outCls, h2c, cwob, outCls,
                                                 1024, 81, 81, 1, 0, 0, 0);

  // ---- stage 3: conv tower (featN no longer needed -> alias cbufA/cbufB) ----
  hipMemsetAsync(cbufA, 0, 67108864, stream);
  hipMemsetAsync(cbufB, 0, 67108864, stream);
  k_conv3m<1><<<dim3(2, 784), 256, 0, stream>>>(r14p, wTb + 0 * 589824, cbufA);
  k_conv3m<1><<<dim3(2, 784), 256, 0, stream>>>(cbufA, wTb + 1 * 589824, cbufB);
  k_conv3m<1><<<dim3(2, 784), 256, 0, stream>>>(cbufB, wTb + 2 * 589824, cbufA);
  k_conv3m<0><<<dim3(2, 784), 256, 0, stream>>>(cbufA, wTb + 3 * 589824, dflat);

  // ---- stage 4: deconv taps + 1x1 class proj scatter ----
  for (int r = 0; r < 2; ++r)
    for (int s = 0; s < 2; ++s) {
      int tap = r * 2 + s;
      k_gemm_bf16<<<dim3(2, 784, 1), 256, 0, stream>>>(
          dflat, wdb + tap * 65536, ddec, dflat, wdb, ddec,
          256, 256, 256, 0, 1, 0, 0);
      k_gemm_bf16<<<dim3(1, 784, 1), 256, 0, stream>>>(
          ddec, mprTb, outMask, ddec, mprTb, outMask,
          256, 81, 0, 2, 0, r, s);
    }
}

// Round 3
// 1747.068 us; speedup vs baseline: 6.6751x; 1.2031x over previous
//
#include <hip/hip_runtime.h>
#include <stdint.h>

#define BB 2
#define CC 256
#define HH 200
#define WW 336
#define NROI 512
#define NCLS 81

typedef __attribute__((ext_vector_type(8))) short bf16x8;
typedef __attribute__((ext_vector_type(4))) float f32x4;

__device__ inline unsigned short f2bf(float f) {
  unsigned int u = __builtin_bit_cast(unsigned int, f);
  u += 0x7fffu + ((u >> 16) & 1u);
  return (unsigned short)(u >> 16);
}
__device__ inline float bf2f(unsigned short h) {
  unsigned int u = ((unsigned int)h) << 16;
  return __builtin_bit_cast(float, u);
}

// async global->LDS, 16 B per lane; LDS dest = uniform base + lane*16
__device__ inline void gl_lds(const void* gp, void* lp) {
  __builtin_amdgcn_global_load_lds(
      (const __attribute__((address_space(1))) unsigned int*)gp,
      (__attribute__((address_space(3))) unsigned int*)lp, 16, 0, 0);
}

// ---------------------------------------------------------------------------
// feat NCHW fp32 -> NHWC bf16, tiled transpose. grid (2100, 8, 2), block 256
// ---------------------------------------------------------------------------
__global__ void k_nchw2nhwc(const float* __restrict__ src, unsigned short* __restrict__ dst) {
  __shared__ float t[32][33];
  int b = blockIdx.z;
  int p0 = blockIdx.x * 32;
  int c0 = blockIdx.y * 32;
  int tx = threadIdx.x & 31, ty = threadIdx.x >> 5;
  const float* s = src + (size_t)b * CC * HH * WW;
  unsigned short* d = dst + (size_t)b * CC * HH * WW;
#pragma unroll
  for (int q = 0; q < 4; ++q)
    t[ty + q * 8][tx] = s[(size_t)(c0 + ty + q * 8) * (HH * WW) + p0 + tx];
  __syncthreads();
#pragma unroll
  for (int q = 0; q < 4; ++q)
    d[(size_t)(p0 + ty + q * 8) * CC + c0 + tx] = f2bf(t[tx][ty + q * 8]);
}

// ---------------------------------------------------------------------------
// Weight repacks (fp32 -> bf16, Bt layout [out][in] so GEMM reads k-contig)
// ---------------------------------------------------------------------------
// 4 conv weights OIHW [256,256,3,3] -> wTb[conv][t][o][c]; grid (2304, 4)
__global__ void k_repack_convw4(const float* __restrict__ w0, const float* __restrict__ w1,
                                const float* __restrict__ w2, const float* __restrict__ w3,
                                unsigned short* __restrict__ wT) {
  int d = blockIdx.x * 256 + threadIdx.x;  // 9*256*256
  if (d >= 589824) return;
  int which = blockIdx.y;
  const float* w = (which == 0) ? w0 : (which == 1) ? w1 : (which == 2) ? w2 : w3;
  int c = d & 255, o = (d >> 8) & 255, t = d >> 16;
  wT[(size_t)which * 589824 + d] = f2bf(w[o * 2304 + c * 9 + t]);
}

// deconv IOHW [256,256,2,2] -> wdb[tap][o][c], spatially flipped:
// out[2i+r,2j+s,o] += x[i,j,c]*mdc[c,o,1-r,1-s]
__global__ void k_repack_deconv(const float* __restrict__ mdc, unsigned short* __restrict__ wd) {
  int d = blockIdx.x * 256 + threadIdx.x;  // 4*256*256
  if (d >= 262144) return;
  int c = d & 255, o = (d >> 8) & 255, tap = d >> 16;
  int r = tap >> 1, s = tap & 1;
  wd[d] = f2bf(mdc[c * 1024 + o * 4 + (1 - r) * 2 + (1 - s)]);
}

// mpr [81,256] -> mprTb[o][c], o padded to 128 with zeros
__global__ void k_repack_mpr(const float* __restrict__ mpr, unsigned short* __restrict__ mT) {
  int d = blockIdx.x * 256 + threadIdx.x;  // 128*256
  if (d >= 32768) return;
  int c = d & 255, o = d >> 8;
  mT[d] = (o < 81) ? f2bf(mpr[o * 256 + c]) : (unsigned short)0;
}

// w1 [12544][1024] -> dst[n][k'] with k' = s*256 + c  (orig k = c*49+s)
// grid (49, 8, 32), block 256
__global__ void k_repack_w1(const float* __restrict__ src, unsigned short* __restrict__ dst) {
  __shared__ float t[32][33];
  int s = blockIdx.x;
  int c0 = blockIdx.y * 32;
  int n0 = blockIdx.z * 32;
  int tx = threadIdx.x & 31, ty = threadIdx.x >> 5;
#pragma unroll
  for (int q = 0; q < 4; ++q)
    t[ty + q * 8][tx] = src[(size_t)((c0 + ty + q * 8) * 49 + s) * 1024 + n0 + tx];
  __syncthreads();
#pragma unroll
  for (int q = 0; q < 4; ++q)
    dst[(size_t)(n0 + ty + q * 8) * 12544 + s * 256 + c0 + tx] = f2bf(t[tx][ty + q * 8]);
}

// generic: src [K][Nreal] f32 -> dst [Nphys][K] bf16 (rows >= Nreal zero)
__global__ void k_transpose_w(const float* __restrict__ src, unsigned short* __restrict__ dst,
                              int K, int Nreal, int Nphys) {
  __shared__ float t[32][33];
  int k0 = blockIdx.x * 32;
  int n0 = blockIdx.y * 32;
  int tx = threadIdx.x & 31, ty = threadIdx.x >> 5;
#pragma unroll
  for (int q = 0; q < 4; ++q) {
    int n = n0 + tx;
    t[ty + q * 8][tx] = (n < Nreal) ? src[(size_t)(k0 + ty + q * 8) * Nreal + n] : 0.f;
  }
  __syncthreads();
#pragma unroll
  for (int q = 0; q < 4; ++q) {
    int n = n0 + ty + q * 8;
    if (n < Nphys) dst[(size_t)n * K + k0 + tx] = f2bf(t[tx][ty + q * 8]);
  }
}

// ---------------------------------------------------------------------------
// zero the 60 border slots (16x16 pad minus 14x14 interior) of the 3 padded
// NHWC conv buffers. grid (480, 3), block 256; each block = 64 rows of 512 B.
// ---------------------------------------------------------------------------
__global__ void k_zero_border(unsigned short* __restrict__ r14p,
                              unsigned short* __restrict__ cbufA,
                              unsigned short* __restrict__ cbufB) {
  unsigned short* base = (blockIdx.y == 0) ? r14p : (blockIdx.y == 1) ? cbufA : cbufB;
  uint4 z = {0u, 0u, 0u, 0u};
#pragma unroll
  for (int q = 0; q < 8; ++q) {
    int lin = blockIdx.x * 2048 + q * 256 + threadIdx.x;
    int row = lin >> 5, u4 = lin & 31;
    int img = row / 60, b = row - img * 60;
    int y, x;
    if (b < 16) { y = 0; x = b; }
    else if (b < 32) { y = 15; x = b - 16; }
    else { int rem = b - 32; y = 1 + (rem >> 1); x = (rem & 1) * 15; }
    int slot = img * 256 + y * 16 + x;
    ((uint4*)base)[(size_t)slot * 32 + u4] = z;
  }
}

// ---------------------------------------------------------------------------
// RoIAlign from bf16 NHWC feat, bf16 out. Block per (n, s), 256 thr = channels.
// OS=7 : out r7b[n*12544 + s*256 + c]           (FC-head A, k' = s*256+c)
// OS=14: out r14p[(n*256 + (y+1)*16 + (x+1))*256 + c]  (padded conv input)
// ---------------------------------------------------------------------------
template <int OS>
__global__ void k_roialign(const unsigned short* __restrict__ featN, const float* __restrict__ boxes,
                           const int* __restrict__ bidx, unsigned short* __restrict__ out) {
  const int S = OS * OS;
  int blk = blockIdx.x;
  int n = blk / S;
  int s = blk - n * S;
  int oy = s / OS, ox = s - oy * OS;
  int c = threadIdx.x;
  float x1 = boxes[n * 4 + 0], y1 = boxes[n * 4 + 1];
  float x2 = boxes[n * 4 + 2], y2 = boxes[n * 4 + 3];
  const unsigned short* fb = featN + (size_t)bidx[n] * HH * WW * CC;
  const float P = (float)(OS * 2);
  float acc = 0.f;
#pragma unroll
  for (int sy = 0; sy < 2; ++sy)
#pragma unroll
    for (int sx = 0; sx < 2; ++sx) {
      float xs = x1 + ((float)(ox * 2 + sx) + 0.5f) / P * (x2 - x1);
      float ys = y1 + ((float)(oy * 2 + sy) + 0.5f) / P * (y2 - y1);
      xs = fminf(fmaxf(xs, 0.f), (float)(WW - 1));
      ys = fminf(fmaxf(ys, 0.f), (float)(HH - 1));
      int x0 = (int)floorf(xs);
      int y0 = (int)floorf(ys);
      int x1i = min(x0 + 1, WW - 1);
      int y1i = min(y0 + 1, HH - 1);
      float lx = xs - (float)x0, ly = ys - (float)y0;
      float f00 = bf2f(fb[((y0 * WW + x0) << 8) + c]);
      float f01 = bf2f(fb[((y0 * WW + x1i) << 8) + c]);
      float f10 = bf2f(fb[((y1i * WW + x0) << 8) + c]);
      float f11 = bf2f(fb[((y1i * WW + x1i) << 8) + c]);
      acc += f00 * (1.f - ly) * (1.f - lx) + f01 * (1.f - ly) * lx +
             f10 * ly * (1.f - lx) + f11 * ly * lx;
    }
  acc *= 0.25f;
  if (OS == 7) {
    out[(size_t)n * 12544 + s * 256 + c] = f2bf(acc);
  } else {
    int slot = n * 256 + (oy + 1) * 16 + (ox + 1);
    out[((size_t)slot << 8) + c] = f2bf(acc);
  }
}

// ---------------------------------------------------------------------------
// bf16 MFMA GEMM, m97 structure: 128x128 tile, BK=32, 4 waves 2x2,
// global_load_lds width 16, A [M][K] bf16, Bt [Nphys][K] bf16.
// mode 0: bf16 out [gm*ldO+gn] (opt relu)
// mode 1: fp32 out [gm*ldO+gn], guarded gn < Nreal
// mode 2: fp32 mask-scatter, guarded gn < Nreal
// ---------------------------------------------------------------------------
#define TM 128
#define TN 128
#define TK 32

__global__ __launch_bounds__(256) void k_gemm_bf16(
    const unsigned short* __restrict__ A0, const unsigned short* __restrict__ Bt0, void* __restrict__ O0p,
    const unsigned short* __restrict__ A1, const unsigned short* __restrict__ Bt1, void* __restrict__ O1p,
    int K, int Nreal, int ldO, int mode, int relu, int ki, int kj) {
  const unsigned short* A = blockIdx.z ? A1 : A0;
  const unsigned short* Bt = blockIdx.z ? Bt1 : Bt0;
  void* Op = blockIdx.z ? O1p : O0p;

  __shared__ unsigned short As[TM * TK];
  __shared__ unsigned short Bs[TN * TK];

  int tid = threadIdx.x, lane = tid & 63, w = tid >> 6;
  int m0 = blockIdx.y * TM, n0 = blockIdx.x * TN;
  int lr = lane >> 2, lc = (lane & 3) * 8;

  const unsigned short* aP[2];
  const unsigned short* bP[2];
  unsigned short* asL[2];
  unsigned short* bsL[2];
#pragma unroll
  for (int s = 0; s < 2; ++s) {
    int seg = w * 2 + s;
    aP[s] = A + (size_t)(m0 + seg * 16 + lr) * K + lc;
    bP[s] = Bt + (size_t)(n0 + seg * 16 + lr) * K + lc;
    asL[s] = As + seg * 512;
    bsL[s] = Bs + seg * 512;
  }

  f32x4 acc[4][4] = {};
  int wm = (w & 1) * 64, wn = (w >> 1) * 64;
  int qa = (lane >> 4) * 8, rl = lane & 15;

  for (int k0 = 0; k0 < K; k0 += TK) {
    gl_lds(aP[0], asL[0]);
    gl_lds(aP[1], asL[1]);
    gl_lds(bP[0], bsL[0]);
    gl_lds(bP[1], bsL[1]);
    aP[0] += TK; aP[1] += TK; bP[0] += TK; bP[1] += TK;
    __syncthreads();
    bf16x8 af[4], bfr[4];
#pragma unroll
    for (int i = 0; i < 4; ++i)
      af[i] = *(const bf16x8*)&As[(wm + i * 16 + rl) * TK + qa];
#pragma unroll
    for (int j = 0; j < 4; ++j)
      bfr[j] = *(const bf16x8*)&Bs[(wn + j * 16 + rl) * TK + qa];
#pragma unroll
    for (int i = 0; i < 4; ++i)
#pragma unroll
      for (int j = 0; j < 4; ++j)
        acc[i][j] = __builtin_amdgcn_mfma_f32_16x16x32_bf16(af[i], bfr[j], acc[i][j], 0, 0, 0);
    __syncthreads();
  }

  int col = lane & 15, rquad = (lane >> 4) * 4;
#pragma unroll
  for (int i = 0; i < 4; ++i) {
#pragma unroll
    for (int j = 0; j < 4; ++j) {
      int gn = n0 + wn + j * 16 + col;
#pragma unroll
      for (int r = 0; r < 4; ++r) {
        int gm = m0 + wm + i * 16 + rquad + r;
        float v = acc[i][j][r];
        if (relu) v = fmaxf(v, 0.f);
        if (mode == 0) {
          ((unsigned short*)Op)[(size_t)gm * ldO + gn] = f2bf(v);
        } else if (mode == 1) {
          if (gn < Nreal) ((float*)Op)[(size_t)gm * ldO + gn] = v;
        } else {
          if (gn < Nreal) {
            int nimg = gm / 196;
            int s2 = gm - nimg * 196;
            int ii = s2 / 14, jj = s2 - ii * 14;
            size_t dst = (((size_t)nimg * 81 + gn) * 28 + (2 * ii + ki)) * 28 + (2 * jj + kj);
            ((float*)Op)[dst] = v;
          }
        }
      }
    }
  }
}

// ---------------------------------------------------------------------------
// FC1 split-K: M=512, N=1024, K=12544 split into 8 slices of 1568.
// grid (8, 4, 16): z -> head = z>>3 (0:box 1:cls), slice = z&7.
// fp32 partials Opart[(head*8+slice)*524288 + m*1024 + n].
// ---------------------------------------------------------------------------
__global__ __launch_bounds__(256) void k_fc1(
    const unsigned short* __restrict__ A, const unsigned short* __restrict__ Bb,
    const unsigned short* __restrict__ Bc, float* __restrict__ Opart) {
  int head = blockIdx.z >> 3, slice = blockIdx.z & 7;
  const unsigned short* Bt = head ? Bc : Bb;

  __shared__ unsigned short As[TM * TK];
  __shared__ unsigned short Bs[TN * TK];

  int tid = threadIdx.x, lane = tid & 63, w = tid >> 6;
  int m0 = blockIdx.y * TM, n0 = blockIdx.x * TN;
  int lr = lane >> 2, lc = (lane & 3) * 8;
  int kbase = slice * 1568;

  const unsigned short* aP[2];
  const unsigned short* bP[2];
  unsigned short* asL[2];
  unsigned short* bsL[2];
#pragma unroll
  for (int s = 0; s < 2; ++s) {
    int seg = w * 2 + s;
    aP[s] = A + (size_t)(m0 + seg * 16 + lr) * 12544 + kbase + lc;
    bP[s] = Bt + (size_t)(n0 + seg * 16 + lr) * 12544 + kbase + lc;
    asL[s] = As + seg * 512;
    bsL[s] = Bs + seg * 512;
  }

  f32x4 acc[4][4] = {};
  int wm = (w & 1) * 64, wn = (w >> 1) * 64;
  int qa = (lane >> 4) * 8, rl = lane & 15;

  for (int k0 = 0; k0 < 1568; k0 += TK) {
    gl_lds(aP[0], asL[0]);
    gl_lds(aP[1], asL[1]);
    gl_lds(bP[0], bsL[0]);
    gl_lds(bP[1], bsL[1]);
    aP[0] += TK; aP[1] += TK; bP[0] += TK; bP[1] += TK;
    __syncthreads();
    bf16x8 af[4], bfr[4];
#pragma unroll
    for (int i = 0; i < 4; ++i)
      af[i] = *(const bf16x8*)&As[(wm + i * 16 + rl) * TK + qa];
#pragma unroll
    for (int j = 0; j < 4; ++j)
      bfr[j] = *(const bf16x8*)&Bs[(wn + j * 16 + rl) * TK + qa];
#pragma unroll
    for (int i = 0; i < 4; ++i)
#pragma unroll
      for (int j = 0; j < 4; ++j)
        acc[i][j] = __builtin_amdgcn_mfma_f32_16x16x32_bf16(af[i], bfr[j], acc[i][j], 0, 0, 0);
    __syncthreads();
  }

  float* O = Opart + (size_t)(head * 8 + slice) * 524288;
  int col = lane & 15, rquad = (lane >> 4) * 4;
#pragma unroll
  for (int i = 0; i < 4; ++i)
#pragma unroll
    for (int j = 0; j < 4; ++j) {
      int gn = n0 + wn + j * 16 + col;
#pragma unroll
      for (int r = 0; r < 4; ++r) {
        int gm = m0 + wm + i * 16 + rquad + r;
        O[(size_t)gm * 1024 + gn] = acc[i][j][r];
      }
    }
}

// reduce 8 split-K partials, relu, -> bf16 h1. grid (2048, 2), block 256.
__global__ void k_fc1red(const float* __restrict__ part, unsigned short* __restrict__ h1b,
                         unsigned short* __restrict__ h1c) {
  int head = blockIdx.y;
  int i = blockIdx.x * 256 + threadIdx.x;  // < 524288
  const float* p = part + (size_t)head * 8 * 524288 + i;
  float s = 0.f;
#pragma unroll
  for (int q = 0; q < 8; ++q) s += p[(size_t)q * 524288];
  unsigned short* h = head ? h1c : h1b;
  h[i] = f2bf(fmaxf(s, 0.f));
}

// ---------------------------------------------------------------------------
// conv3x3 SAME + relu as implicit bf16 MFMA GEMM over padded NHWC input.
// act: [512*256 slots][256] bf16 (16x16 padded spatial); wt: [9][o][c] bf16.
// M = 100352 (grid.y=784), N = 256 (grid.x=2), K = 9*256 tap-major.
// PADOUT=1: write padded interior; PADOUT=0: flat [100352][256].
// ---------------------------------------------------------------------------
template <int PADOUT>
__global__ __launch_bounds__(256) void k_conv3m(const unsigned short* __restrict__ act,
                                                const unsigned short* __restrict__ wt,
                                                unsigned short* __restrict__ out) {
  __shared__ unsigned short As[TM * TK];
  __shared__ unsigned short Bs[TN * TK];

  int tid = threadIdx.x, lane = tid & 63, w = tid >> 6;
  int m0 = blockIdx.y * TM, n0 = blockIdx.x * TN;
  int lr = lane >> 2, lc = (lane & 3) * 8;

  const unsigned short* aB[2];
  const unsigned short* bB[2];
  unsigned short* asL[2];
  unsigned short* bsL[2];
#pragma unroll
  for (int s = 0; s < 2; ++s) {
    int seg = w * 2 + s;
    int m = m0 + seg * 16 + lr;
    int n = m / 196;
    int rem = m - n * 196;
    int y = rem / 14, x = rem - y * 14;
    int slot = n * 256 + (y + 1) * 16 + (x + 1);
    aB[s] = act + ((size_t)slot << 8) + lc;
    bB[s] = wt + (size_t)(n0 + seg * 16 + lr) * 256 + lc;
    asL[s] = As + seg * 512;
    bsL[s] = Bs + seg * 512;
  }

  f32x4 acc[4][4] = {};
  int wm = (w & 1) * 64, wn = (w >> 1) * 64;
  int qa = (lane >> 4) * 8, rl = lane & 15;

  for (int ky = -1; ky <= 1; ++ky) {
    for (int kx = -1; kx <= 1; ++kx) {
      int aoff = (ky * 16 + kx) * 256;
      int boff = ((ky + 1) * 3 + (kx + 1)) * 65536;
      for (int c0 = 0; c0 < 256; c0 += TK) {
        gl_lds(aB[0] + aoff + c0, asL[0]);
        gl_lds(aB[1] + aoff + c0, asL[1]);
        gl_lds(bB[0] + boff + c0, bsL[0]);
        gl_lds(bB[1] + boff + c0, bsL[1]);
        __syncthreads();
        bf16x8 af[4], bfr[4];
#pragma unroll
        for (int i = 0; i < 4; ++i)
          af[i] = *(const bf16x8*)&As[(wm + i * 16 + rl) * TK + qa];
#pragma unroll
        for (int j = 0; j < 4; ++j)
          bfr[j] = *(const bf16x8*)&Bs[(wn + j * 16 + rl) * TK + qa];
#pragma unroll
        for (int i = 0; i < 4; ++i)
#pragma unroll
          for (int j = 0; j < 4; ++j)
            acc[i][j] = __builtin_amdgcn_mfma_f32_16x16x32_bf16(af[i], bfr[j], acc[i][j], 0, 0, 0);
        __syncthreads();
      }
    }
  }

  int col = lane & 15, rquad = (lane >> 4) * 4;
#pragma unroll
  for (int i = 0; i < 4; ++i) {
#pragma unroll
    for (int r = 0; r < 4; ++r) {
      int gm = m0 + wm + i * 16 + rquad + r;
      size_t rowbase;
      if (PADOUT) {
        int n = gm / 196;
        int rem = gm - n * 196;
        int y = rem / 14, x = rem - y * 14;
        rowbase = ((size_t)(n * 256 + (y + 1) * 16 + (x + 1))) << 8;
      } else {
        rowbase = (size_t)gm << 8;
      }
#pragma unroll
      for (int j = 0; j < 4; ++j) {
        int gn = n0 + wn + j * 16 + col;
        out[rowbase + gn] = f2bf(fmaxf(acc[i][j][r], 0.f));
      }
    }
  }
}

// ---------------------------------------------------------------------------
// kernel_launch
// ---------------------------------------------------------------------------
extern "C" void kernel_launch(void* const* d_in, const int* in_sizes, int n_in,
                              void* d_out, int out_size, void* d_ws, size_t ws_size,
                              hipStream_t stream) {
  (void)in_sizes; (void)n_in; (void)out_size; (void)ws_size;
  const float* feat = (const float*)d_in[0];
  const float* boxes = (const float*)d_in[1];
  const float* bw1 = (const float*)d_in[2];
  const float* bw2 = (const float*)d_in[3];
  const float* bwo = (const float*)d_in[4];
  const float* cw1 = (const float*)d_in[5];
  const float* cw2 = (const float*)d_in[6];
  const float* cwo = (const float*)d_in[7];
  const float* m1 = (const float*)d_in[8];
  const float* m2 = (const float*)d_in[9];
  const float* m3 = (const float*)d_in[10];
  const float* m4 = (const float*)d_in[11];
  const float* mdc = (const float*)d_in[12];
  const float* mpr = (const float*)d_in[13];
  const int* bidx = (const int*)d_in[14];

  // ---- workspace layout (bytes; total 384,761,856 <= proven 386,465,792) ----
  char* p = (char*)d_ws;
  unsigned short* featN = (unsigned short*)p; p += 68812800;  // bf16 NHWC feat
  unsigned short* cbufA = featN;                              // alias (67,108,864 B)
  unsigned short* cbufB = (unsigned short*)p; p += 67108864;
  float* fc1part = (float*)cbufB;                             // alias (33,554,432 B)
  unsigned short* r14p = (unsigned short*)p;  p += 67108864;  // padded conv input
  unsigned short* dflat = (unsigned short*)p; p += 51380224;  // conv4 out, flat
  unsigned short* ddec = (unsigned short*)p;  p += 51380224;  // deconv tap out
  unsigned short* r7b = (unsigned short*)p;   p += 12845056;  // [512][12544]
  unsigned short* h1b = (unsigned short*)p;   p += 1048576;
  unsigned short* h1c = (unsigned short*)p;   p += 1048576;
  unsigned short* h2b = (unsigned short*)p;   p += 1048576;
  unsigned short* h2c = (unsigned short*)p;   p += 1048576;
  unsigned short* wTb = (unsigned short*)p;   p += 4718592;   // 4 convs [9][o][c]
  unsigned short* wdb = (unsigned short*)p;   p += 524288;    // [4][o][c]
  unsigned short* mprTb = (unsigned short*)p; p += 65536;     // [128][256]
  unsigned short* bw1b = (unsigned short*)p;  p += 25690112;  // [1024][12544]
  unsigned short* cw1b = (unsigned short*)p;  p += 25690112;
  unsigned short* bw2b = (unsigned short*)p;  p += 2097152;   // [1024][1024]
  unsigned short* cw2b = (unsigned short*)p;  p += 2097152;
  unsigned short* bwob = (unsigned short*)p;  p += 786432;    // [384][1024]
  unsigned short* cwob = (unsigned short*)p;  p += 262144;    // [128][1024]

  float* outBox = (float*)d_out;              // [512][324]
  float* outCls = outBox + 512 * 324;         // [512][81]
  float* outMask = outCls + 512 * 81;         // [512][81][28][28]

  // ---- stage 0: layout transforms ----
  k_nchw2nhwc<<<dim3(2100, 8, 2), 256, 0, stream>>>(feat, featN);
  k_repack_convw4<<<dim3(2304, 4), 256, 0, stream>>>(m1, m2, m3, m4, wTb);
  k_repack_deconv<<<dim3(1024), 256, 0, stream>>>(mdc, wdb);
  k_repack_mpr<<<dim3(128), 256, 0, stream>>>(mpr, mprTb);
  k_repack_w1<<<dim3(49, 8, 32), 256, 0, stream>>>(bw1, bw1b);
  k_repack_w1<<<dim3(49, 8, 32), 256, 0, stream>>>(cw1, cw1b);
  k_transpose_w<<<dim3(32, 32), 256, 0, stream>>>(bw2, bw2b, 1024, 1024, 1024);
  k_transpose_w<<<dim3(32, 32), 256, 0, stream>>>(cw2, cw2b, 1024, 1024, 1024);
  k_transpose_w<<<dim3(32, 12), 256, 0, stream>>>(bwo, bwob, 1024, 324, 384);
  k_transpose_w<<<dim3(32, 4), 256, 0, stream>>>(cwo, cwob, 1024, 81, 128);

  // ---- stage 1: RoIAlign (interiors; borders of r14p zeroed later) ----
  k_roialign<7><<<dim3(512 * 49), 256, 0, stream>>>(featN, boxes, bidx, r7b);
  k_roialign<14><<<dim3(512 * 196), 256, 0, stream>>>(featN, boxes, bidx, r14p);

  // ---- stage 2: FC heads. FC1 split-K=8 over both heads (partials alias cbufB) ----
  k_fc1<<<dim3(8, 4, 16), 256, 0, stream>>>(r7b, bw1b, cw1b, fc1part);
  k_fc1red<<<dim3(2048, 2), 256, 0, stream>>>(fc1part, h1b, h1c);
  k_gemm_bf16<<<dim3(8, 4, 2), 256, 0, stream>>>(h1b, bw2b, h2b, h1c, cw2b, h2c,
                                                 1024, 1024, 1024, 0, 1, 0, 0);
  k_gemm_bf16<<<dim3(3, 4, 1), 256, 0, stream>>>(h2b, bwob, outBox, h2b, bwob, outBox,
                                                 1024, 324, 324, 1, 0, 0, 0);
  k_gemm_bf16<<<dim3(1, 4, 1), 256, 0, stream>>>(h2c, cwob, outCls, h2c, cwob, outCls,
                                                 1024, 81, 81, 1, 0, 0, 0);

  // ---- stage 3: conv tower. Border zeros AFTER fc1 (partials aliased cbufB)
  //      and AFTER roialign (cbufA aliases featN). ----
  k_zero_border<<<dim3(480, 3), 256, 0, stream>>>(r14p, cbufA, cbufB);
  k_conv3m<1><<<dim3(2, 784), 256, 0, stream>>>(r14p, wTb + 0 * 589824, cbufA);
  k_conv3m<1><<<dim3(2, 784), 256, 0, stream>>>(cbufA, wTb + 1 * 589824, cbufB);
  k_conv3m<1><<<dim3(2, 784), 256, 0, stream>>>(cbufB, wTb + 2 * 589824, cbufA);
  k_conv3m<0><<<dim3(2, 784), 256, 0, stream>>>(cbufA, wTb + 3 * 589824, dflat);

  // ---- stage 4: deconv taps + 1x1 class proj scatter ----
  for (int r = 0; r < 2; ++r)
    for (int s = 0; s < 2; ++s) {
      int tap = r * 2 + s;
      k_gemm_bf16<<<dim3(2, 784, 1), 256, 0, stream>>>(
          dflat, wdb + tap * 65536, ddec, dflat, wdb, ddec,
          256, 256, 256, 0, 1, 0, 0);
      k_gemm_bf16<<<dim3(1, 784, 1), 256, 0, stream>>>(
          ddec, mprTb, outMask, ddec, mprTb, outMask,
          256, 81, 0, 2, 0, r, s);
    }
}